// Round 1
// baseline (1835.782 us; speedup 1.0000x reference)
//
#include <hip/hip_runtime.h>
#include <math.h>

#define N_NODES 50000
#define N_EDGES 500000
#define NLAYERS 6
#define NEG_SLOPE 0.2f
#define LN_EPS 1e-5f
#define SCAN_T 1024
#define MM_ROWS 32

__device__ __forceinline__ float wave_sum64(float v) {
#pragma unroll
    for (int m = 32; m >= 1; m >>= 1) v += __shfl_xor(v, m, 64);
    return v;
}

// ---------------- CSR build ----------------
__global__ void count_deg(const int* __restrict__ dst, int* __restrict__ deg) {
    int i = blockIdx.x * blockDim.x + threadIdx.x;
    if (i < N_EDGES) atomicAdd(&deg[dst[i]], 1);
}

__global__ void scan_deg(const int* __restrict__ deg, int* __restrict__ row_ptr,
                         int* __restrict__ pos) {
    __shared__ int part[SCAN_T];
    int t = threadIdx.x;
    const int n = N_NODES;
    const int chunk = (n + SCAN_T - 1) / SCAN_T;
    int b0 = t * chunk;
    int b1 = min(b0 + chunk, n);
    int s = 0;
    for (int i = b0; i < b1; ++i) s += deg[i];
    part[t] = s;
    __syncthreads();
    for (int offs = 1; offs < SCAN_T; offs <<= 1) {
        int v = (t >= offs) ? part[t - offs] : 0;
        __syncthreads();
        part[t] += v;
        __syncthreads();
    }
    int run = (t == 0) ? 0 : part[t - 1];
    for (int i = b0; i < b1; ++i) {
        row_ptr[i] = run;
        pos[i] = run;
        run += deg[i];
    }
    if (b1 == n) row_ptr[n] = run;  // all threads whose chunk ends at n write total
}

__global__ void scatter_edges(const int* __restrict__ dst, int* __restrict__ pos,
                              int* __restrict__ eidx) {
    int i = blockIdx.x * blockDim.x + threadIdx.x;
    if (i < N_EDGES) {
        int p = atomicAdd(&pos[dst[i]], 1);
        eidx[p] = i;
    }
}

// ---------------- dense [n,64] @ [64,64] + b ----------------
__global__ void mm64_kernel(const float* __restrict__ X, const float* __restrict__ W,
                            const float* __restrict__ b, float* __restrict__ Y, int n) {
    __shared__ float Ws[64][64];
    __shared__ float bs[64];
    int t = threadIdx.x;
    for (int i = t; i < 64 * 64; i += 256) Ws[i >> 6][i & 63] = W[i];
    if (t < 64) bs[t] = b[t];
    __syncthreads();
    int lane = t & 63;
    int rg = t >> 6;
    int base = blockIdx.x * MM_ROWS;
    for (int r = rg; r < MM_ROWS; r += 4) {
        int row = base + r;
        if (row >= n) break;
        const float* x = X + (size_t)row * 64;
        float acc = bs[lane];
#pragma unroll
        for (int k = 0; k < 64; ++k) acc = fmaf(x[k], Ws[k][lane], acc);
        Y[(size_t)row * 64 + lane] = acc;
    }
}

// ---------------- per-edge attention scores ----------------
__global__ void edge_score_kernel(const float* __restrict__ fs, const float* __restrict__ fd,
                                  const int* __restrict__ src, const int* __restrict__ dst,
                                  const float* __restrict__ a, float* __restrict__ score) {
    int lane = threadIdx.x & 63;
    int e = blockIdx.x * (blockDim.x >> 6) + (threadIdx.x >> 6);
    if (e >= N_EDGES) return;
    int s = src[e], d = dst[e];
    float v = fs[(size_t)s * 64 + lane] + fd[(size_t)d * 64 + lane];
    v = (v > 0.f) ? v : NEG_SLOPE * v;
    float p = a[lane] * v;
    p = wave_sum64(p);
    if (lane == 0) score[e] = p;
}

// ---------------- per-node: softmax + aggregate + LN + GELU + residual ----------------
__global__ void node_agg_kernel(const float* __restrict__ fs, const float* __restrict__ score,
                                const int* __restrict__ row_ptr, const int* __restrict__ eidx,
                                const int* __restrict__ src, const float* __restrict__ gamma,
                                const float* __restrict__ beta, float* __restrict__ h) {
    int lane = threadIdx.x & 63;
    int n = blockIdx.x * (blockDim.x >> 6) + (threadIdx.x >> 6);
    if (n >= N_NODES) return;
    int beg = row_ptr[n], end = row_ptr[n + 1];

    // online segment softmax (scalar, replicated across lanes)
    float m = -INFINITY, dsum = 0.f;
    for (int j = beg; j < end; ++j) {
        float sc = score[eidx[j]];
        if (sc > m) {
            dsum = dsum * expf(m - sc) + 1.f;
            m = sc;
        } else {
            dsum += expf(sc - m);
        }
    }
    float inv = (dsum > 0.f) ? 1.f / dsum : 0.f;

    float acc = 0.f;
    for (int j = beg; j < end; ++j) {
        int e = eidx[j];
        float w = expf(score[e] - m) * inv;
        acc = fmaf(w, fs[(size_t)src[e] * 64 + lane], acc);
    }

    // layernorm over 64 features (one per lane)
    float mean = wave_sum64(acc) * (1.f / 64.f);
    float dev = acc - mean;
    float var = wave_sum64(dev * dev) * (1.f / 64.f);
    float tval = dev * rsqrtf(var + LN_EPS) * gamma[lane] + beta[lane];

    // exact gelu
    float g = 0.5f * tval * (1.f + erff(tval * 0.70710678118654752f));
    h[(size_t)n * 64 + lane] += g;
}

// ---------------- output projection [n,64] @ [64,8] + b ----------------
__global__ void out_proj_kernel(const float* __restrict__ h, const float* __restrict__ W,
                                const float* __restrict__ b, float* __restrict__ out) {
    __shared__ float Ws[64 * 8];
    __shared__ float bs[8];
    __shared__ float Hs[32][65];
    int t = threadIdx.x;
    if (t < 512) {
        // only 256 threads; load in two steps
    }
    for (int i = t; i < 512; i += 256) Ws[i] = W[i];
    if (t < 8) bs[t] = b[t];
    int n0 = blockIdx.x * 32;
    for (int i = t; i < 32 * 64; i += 256) {
        int r = i >> 6, c = i & 63;
        int n = n0 + r;
        Hs[r][c] = (n < N_NODES) ? h[(size_t)n * 64 + c] : 0.f;
    }
    __syncthreads();
    int nl = t >> 3, o = t & 7;
    int n = n0 + nl;
    if (n >= N_NODES) return;
    float acc = bs[o];
#pragma unroll
    for (int k = 0; k < 64; ++k) acc = fmaf(Hs[nl][k], Ws[k * 8 + o], acc);
    out[(size_t)n * 8 + o] = acc;
}

extern "C" void kernel_launch(void* const* d_in, const int* in_sizes, int n_in,
                              void* d_out, int out_size, void* d_ws, size_t ws_size,
                              hipStream_t stream) {
    const float* nodes = (const float*)d_in[0];
    const int* src = (const int*)d_in[1];
    const int* dst = (const int*)d_in[2];
    const float* w_in = (const float*)d_in[3];
    const float* b_in = (const float*)d_in[4];
    const float* w_src = (const float*)d_in[5];
    const float* b_src = (const float*)d_in[6];
    const float* w_dst = (const float*)d_in[7];
    const float* b_dst = (const float*)d_in[8];
    const float* attn = (const float*)d_in[9];
    const float* gamma = (const float*)d_in[10];
    const float* beta = (const float*)d_in[11];
    const float* w_out = (const float*)d_in[12];
    const float* b_out = (const float*)d_in[13];
    float* out = (float*)d_out;

    char* ws = (char*)d_ws;
    size_t off = 0;
    auto alloc = [&](size_t bytes) {
        void* p = ws + off;
        off += (bytes + 255) & ~(size_t)255;
        return p;
    };
    float* h = (float*)alloc((size_t)N_NODES * 64 * 4);
    float* fs = (float*)alloc((size_t)N_NODES * 64 * 4);
    float* fd = (float*)alloc((size_t)N_NODES * 64 * 4);
    float* score = (float*)alloc((size_t)N_EDGES * 4);
    int* deg = (int*)alloc((size_t)N_NODES * 4);
    int* row_ptr = (int*)alloc((size_t)(N_NODES + 1) * 4);
    int* pos = (int*)alloc((size_t)N_NODES * 4);
    int* eidx = (int*)alloc((size_t)N_EDGES * 4);

    // CSR by dst (graph is static across layers)
    hipMemsetAsync(deg, 0, (size_t)N_NODES * 4, stream);
    count_deg<<<(N_EDGES + 255) / 256, 256, 0, stream>>>(dst, deg);
    scan_deg<<<1, SCAN_T, 0, stream>>>(deg, row_ptr, pos);
    scatter_edges<<<(N_EDGES + 255) / 256, 256, 0, stream>>>(dst, pos, eidx);

    // input projection
    mm64_kernel<<<(N_NODES + MM_ROWS - 1) / MM_ROWS, 256, 0, stream>>>(nodes, w_in, b_in, h,
                                                                       N_NODES);

    for (int l = 0; l < NLAYERS; ++l) {
        mm64_kernel<<<(N_NODES + MM_ROWS - 1) / MM_ROWS, 256, 0, stream>>>(
            h, w_src + (size_t)l * 4096, b_src + (size_t)l * 64, fs, N_NODES);
        mm64_kernel<<<(N_NODES + MM_ROWS - 1) / MM_ROWS, 256, 0, stream>>>(
            h, w_dst + (size_t)l * 4096, b_dst + (size_t)l * 64, fd, N_NODES);
        edge_score_kernel<<<(N_EDGES + 3) / 4, 256, 0, stream>>>(fs, fd, src, dst,
                                                                 attn + (size_t)l * 64, score);
        node_agg_kernel<<<(N_NODES + 3) / 4, 256, 0, stream>>>(
            fs, score, row_ptr, eidx, src, gamma + (size_t)l * 64, beta + (size_t)l * 64, h);
    }

    out_proj_kernel<<<(N_NODES + 31) / 32, 256, 0, stream>>>(h, w_out, b_out, out);
}

// Round 2
// 848.714 us; speedup vs baseline: 2.1630x; 2.1630x over previous
//
#include <hip/hip_runtime.h>
#include <math.h>

#define N_NODES 50000
#define N_EDGES 500000
#define NLAYERS 6
#define NEG_SLOPE 0.2f
#define LN_EPS 1e-5f
#define SCAN_T 1024
#define MM_ROWS 32

__device__ __forceinline__ float wave_sum64(float v) {
#pragma unroll
    for (int m = 32; m >= 1; m >>= 1) v += __shfl_xor(v, m, 64);
    return v;
}

// ---------------- CSR build ----------------
__global__ void count_deg(const int* __restrict__ dst, int* __restrict__ deg) {
    int i = blockIdx.x * blockDim.x + threadIdx.x;
    if (i < N_EDGES) atomicAdd(&deg[dst[i]], 1);
}

__global__ void scan_deg(const int* __restrict__ deg, int* __restrict__ row_ptr,
                         int* __restrict__ pos) {
    __shared__ int part[SCAN_T];
    int t = threadIdx.x;
    const int n = N_NODES;
    const int chunk = (n + SCAN_T - 1) / SCAN_T;
    int b0 = t * chunk;
    int b1 = min(b0 + chunk, n);
    int s = 0;
    for (int i = b0; i < b1; ++i) s += deg[i];
    part[t] = s;
    __syncthreads();
    for (int offs = 1; offs < SCAN_T; offs <<= 1) {
        int v = (t >= offs) ? part[t - offs] : 0;
        __syncthreads();
        part[t] += v;
        __syncthreads();
    }
    int run = (t == 0) ? 0 : part[t - 1];
    for (int i = b0; i < b1; ++i) {
        row_ptr[i] = run;
        pos[i] = run;
        run += deg[i];
    }
    if (b1 == n) row_ptr[n] = run;
}

__global__ void scatter_edges(const int* __restrict__ dst, const int* __restrict__ src,
                              int* __restrict__ pos, int* __restrict__ srcs) {
    int i = blockIdx.x * blockDim.x + threadIdx.x;
    if (i < N_EDGES) {
        int p = atomicAdd(&pos[dst[i]], 1);
        srcs[p] = src[i];
    }
}

// ---------------- dense [n,64] @ [64,64] + b (input projection) ----------------
__global__ void mm64_kernel(const float* __restrict__ X, const float* __restrict__ W,
                            const float* __restrict__ b, float* __restrict__ Y, int n) {
    __shared__ float Ws[64][64];
    __shared__ float bs[64];
    int t = threadIdx.x;
    for (int i = t; i < 64 * 64; i += 256) Ws[i >> 6][i & 63] = W[i];
    if (t < 64) bs[t] = b[t];
    __syncthreads();
    int lane = t & 63;
    int rg = t >> 6;
    int base = blockIdx.x * MM_ROWS;
    for (int r = rg; r < MM_ROWS; r += 4) {
        int row = base + r;
        if (row >= n) break;
        const float* x = X + (size_t)row * 64;
        float acc = bs[lane];
#pragma unroll
        for (int k = 0; k < 64; ++k) acc = fmaf(x[k], Ws[k][lane], acc);
        Y[(size_t)row * 64 + lane] = acc;
    }
}

// ---------------- dual dense: fs = h@Ws+bs, fd = h@Wd+bd, register-blocked ----------------
#define DROWS 32
__global__ void mm64_dual(const float* __restrict__ X, const float* __restrict__ Wsg,
                          const float* __restrict__ bsg, const float* __restrict__ Wdg,
                          const float* __restrict__ bdg, float* __restrict__ FS,
                          float* __restrict__ FD, int n) {
    __shared__ float Ws[64][64];
    __shared__ float Wd[64][64];
    __shared__ float xs[4][8][64];
    __shared__ float bsh[64], bdh[64];
    int t = threadIdx.x;
    for (int i = t; i < 4096; i += 256) {
        Ws[i >> 6][i & 63] = Wsg[i];
        Wd[i >> 6][i & 63] = Wdg[i];
    }
    if (t < 64) {
        bsh[t] = bsg[t];
        bdh[t] = bdg[t];
    }
    int lane = t & 63, wv = t >> 6;
    int r0 = blockIdx.x * DROWS + wv * 8;
#pragma unroll
    for (int r = 0; r < 8; ++r) {
        int row = r0 + r;
        xs[wv][r][lane] = (row < n) ? X[(size_t)row * 64 + lane] : 0.f;
    }
    __syncthreads();
    float as[8], ad[8];
    float bsv = bsh[lane], bdv = bdh[lane];
#pragma unroll
    for (int r = 0; r < 8; ++r) {
        as[r] = bsv;
        ad[r] = bdv;
    }
    for (int k4 = 0; k4 < 16; ++k4) {
        int k = k4 * 4;
        float ws0 = Ws[k + 0][lane], ws1 = Ws[k + 1][lane];
        float ws2 = Ws[k + 2][lane], ws3 = Ws[k + 3][lane];
        float wd0 = Wd[k + 0][lane], wd1 = Wd[k + 1][lane];
        float wd2 = Wd[k + 2][lane], wd3 = Wd[k + 3][lane];
#pragma unroll
        for (int r = 0; r < 8; ++r) {
            float4 xv = *(const float4*)&xs[wv][r][k];
            as[r] = fmaf(xv.x, ws0, as[r]);
            as[r] = fmaf(xv.y, ws1, as[r]);
            as[r] = fmaf(xv.z, ws2, as[r]);
            as[r] = fmaf(xv.w, ws3, as[r]);
            ad[r] = fmaf(xv.x, wd0, ad[r]);
            ad[r] = fmaf(xv.y, wd1, ad[r]);
            ad[r] = fmaf(xv.z, wd2, ad[r]);
            ad[r] = fmaf(xv.w, wd3, ad[r]);
        }
    }
#pragma unroll
    for (int r = 0; r < 8; ++r) {
        int row = r0 + r;
        if (row < n) {
            FS[(size_t)row * 64 + lane] = as[r];
            FD[(size_t)row * 64 + lane] = ad[r];
        }
    }
}

// ---------------- fused per-node: scores + online softmax + aggregate + LN + GELU + residual
#define WPB 4  // waves per block
#define NPW 4  // nodes per wave
__global__ void node_fused_kernel(const float* __restrict__ fs, const float* __restrict__ fd,
                                  const int* __restrict__ row_ptr, const int* __restrict__ srcs,
                                  const float* __restrict__ attn, const float* __restrict__ gamma,
                                  const float* __restrict__ beta, float* __restrict__ h) {
    int lane = threadIdx.x & 63;
    int wv = threadIdx.x >> 6;
    float aL = attn[lane], gL = gamma[lane], bL = beta[lane];
    int base = blockIdx.x * (WPB * NPW) + wv * NPW;
    for (int i = 0; i < NPW; ++i) {
        int n = base + i;
        if (n >= N_NODES) break;
        int beg = row_ptr[n], end = row_ptr[n + 1];
        float fdv = fd[(size_t)n * 64 + lane];
        float m = -INFINITY, d = 0.f, acc = 0.f;
        // software-pipelined gather + online softmax
        float row = 0.f;
        if (beg < end) {
            int sn = srcs[beg];
            row = fs[(size_t)sn * 64 + lane];
        }
        for (int j = beg; j < end;) {
            float cur = row;
            int jn = j + 1;
            if (jn < end) {
                int sn2 = srcs[jn];
                row = fs[(size_t)sn2 * 64 + lane];
            }
            float v = cur + fdv;
            v = (v > 0.f) ? v : NEG_SLOPE * v;
            float sc = wave_sum64(aL * v);
            if (sc > m) {
                float sca = __expf(m - sc);
                d *= sca;
                acc *= sca;
                m = sc;
            }
            float w = __expf(sc - m);
            d += w;
            acc = fmaf(w, cur, acc);
            j = jn;
        }
        float inv = (d > 0.f) ? 1.f / d : 0.f;
        acc *= inv;
        // layernorm over 64 features (one per lane)
        float mean = wave_sum64(acc) * 0.015625f;
        float dev = acc - mean;
        float var = wave_sum64(dev * dev) * 0.015625f;
        float tval = dev * rsqrtf(var + LN_EPS) * gL + bL;
        // exact gelu
        float g = 0.5f * tval * (1.f + erff(tval * 0.70710678118654752f));
        h[(size_t)n * 64 + lane] += g;
    }
}

// ---------------- output projection [n,64] @ [64,8] + b ----------------
__global__ void out_proj_kernel(const float* __restrict__ h, const float* __restrict__ W,
                                const float* __restrict__ b, float* __restrict__ out) {
    __shared__ float Ws[64 * 8];
    __shared__ float bs[8];
    __shared__ float Hs[32][65];
    int t = threadIdx.x;
    for (int i = t; i < 512; i += 256) Ws[i] = W[i];
    if (t < 8) bs[t] = b[t];
    int n0 = blockIdx.x * 32;
    for (int i = t; i < 32 * 64; i += 256) {
        int r = i >> 6, c = i & 63;
        int n = n0 + r;
        Hs[r][c] = (n < N_NODES) ? h[(size_t)n * 64 + c] : 0.f;
    }
    __syncthreads();
    int nl = t >> 3, o = t & 7;
    int n = n0 + nl;
    if (n >= N_NODES) return;
    float acc = bs[o];
#pragma unroll
    for (int k = 0; k < 64; ++k) acc = fmaf(Hs[nl][k], Ws[k * 8 + o], acc);
    out[(size_t)n * 8 + o] = acc;
}

extern "C" void kernel_launch(void* const* d_in, const int* in_sizes, int n_in,
                              void* d_out, int out_size, void* d_ws, size_t ws_size,
                              hipStream_t stream) {
    const float* nodes = (const float*)d_in[0];
    const int* src = (const int*)d_in[1];
    const int* dst = (const int*)d_in[2];
    const float* w_in = (const float*)d_in[3];
    const float* b_in = (const float*)d_in[4];
    const float* w_src = (const float*)d_in[5];
    const float* b_src = (const float*)d_in[6];
    const float* w_dst = (const float*)d_in[7];
    const float* b_dst = (const float*)d_in[8];
    const float* attn = (const float*)d_in[9];
    const float* gamma = (const float*)d_in[10];
    const float* beta = (const float*)d_in[11];
    const float* w_out = (const float*)d_in[12];
    const float* b_out = (const float*)d_in[13];
    float* out = (float*)d_out;

    char* ws = (char*)d_ws;
    size_t off = 0;
    auto alloc = [&](size_t bytes) {
        void* p = ws + off;
        off += (bytes + 255) & ~(size_t)255;
        return p;
    };
    float* h = (float*)alloc((size_t)N_NODES * 64 * 4);
    float* fs = (float*)alloc((size_t)N_NODES * 64 * 4);
    float* fd = (float*)alloc((size_t)N_NODES * 64 * 4);
    int* deg = (int*)alloc((size_t)N_NODES * 4);
    int* row_ptr = (int*)alloc((size_t)(N_NODES + 1) * 4);
    int* pos = (int*)alloc((size_t)N_NODES * 4);
    int* srcs = (int*)alloc((size_t)N_EDGES * 4);

    // CSR by dst (graph is static across layers); srcs[] = src id in CSR slot order
    hipMemsetAsync(deg, 0, (size_t)N_NODES * 4, stream);
    count_deg<<<(N_EDGES + 255) / 256, 256, 0, stream>>>(dst, deg);
    scan_deg<<<1, SCAN_T, 0, stream>>>(deg, row_ptr, pos);
    scatter_edges<<<(N_EDGES + 255) / 256, 256, 0, stream>>>(dst, src, pos, srcs);

    // input projection
    mm64_kernel<<<(N_NODES + MM_ROWS - 1) / MM_ROWS, 256, 0, stream>>>(nodes, w_in, b_in, h,
                                                                       N_NODES);

    for (int l = 0; l < NLAYERS; ++l) {
        mm64_dual<<<(N_NODES + DROWS - 1) / DROWS, 256, 0, stream>>>(
            h, w_src + (size_t)l * 4096, b_src + (size_t)l * 64, w_dst + (size_t)l * 4096,
            b_dst + (size_t)l * 64, fs, fd, N_NODES);
        node_fused_kernel<<<(N_NODES + WPB * NPW - 1) / (WPB * NPW), 256, 0, stream>>>(
            fs, fd, row_ptr, srcs, attn + (size_t)l * 64, gamma + (size_t)l * 64,
            beta + (size_t)l * 64, h);
    }

    out_proj_kernel<<<(N_NODES + 31) / 32, 256, 0, stream>>>(h, w_out, b_out, out);
}

// Round 3
// 657.690 us; speedup vs baseline: 2.7913x; 1.2904x over previous
//
#include <hip/hip_runtime.h>
#include <math.h>

#define N_NODES 50000
#define N_EDGES 500000
#define NLAYERS 6
#define NEG_SLOPE 0.2f
#define LN_EPS 1e-5f
#define MM_ROWS 32
#define SCAN_B 1024
#define NSCAN_BLOCKS ((N_NODES + SCAN_B - 1) / SCAN_B)  // 49

__device__ __forceinline__ float wave_sum64(float v) {
#pragma unroll
    for (int m = 32; m >= 1; m >>= 1) v += __shfl_xor(v, m, 64);
    return v;
}

__device__ __forceinline__ int wave_incl_scan(int v, int lane) {
#pragma unroll
    for (int offs = 1; offs < 64; offs <<= 1) {
        int t = __shfl_up(v, offs, 64);
        if (lane >= offs) v += t;
    }
    return v;
}

// ---------------- CSR build ----------------
__global__ void count_deg(const int* __restrict__ dst, int* __restrict__ deg) {
    int i = blockIdx.x * blockDim.x + threadIdx.x;
    if (i < N_EDGES) atomicAdd(&deg[dst[i]], 1);
}

// intra-block exclusive scan; partial results -> row_ptr, block totals -> bsum
__global__ void scan1(const int* __restrict__ deg, int* __restrict__ row_ptr,
                      int* __restrict__ bsum) {
    int i = blockIdx.x * SCAN_B + threadIdx.x;
    int lane = threadIdx.x & 63, wv = threadIdx.x >> 6;
    int v = (i < N_NODES) ? deg[i] : 0;
    int incl = wave_incl_scan(v, lane);
    __shared__ int wtot[16];
    if (lane == 63) wtot[wv] = incl;
    __syncthreads();
    if (wv == 0) {
        int wval = (lane < 16) ? wtot[lane] : 0;
        int ws = wave_incl_scan(wval, lane);
        if (lane < 16) wtot[lane] = ws - wval;  // exclusive wave offset
    }
    __syncthreads();
    int excl = incl - v + wtot[wv];
    if (i < N_NODES) row_ptr[i] = excl;
    if (threadIdx.x == SCAN_B - 1) bsum[blockIdx.x] = excl + v;
}

// scan 49 block sums with one wave
__global__ void scan2(const int* __restrict__ bsum, int* __restrict__ boffs) {
    int lane = threadIdx.x;
    int v = (lane < NSCAN_BLOCKS) ? bsum[lane] : 0;
    int incl = wave_incl_scan(v, lane);
    if (lane < NSCAN_BLOCKS) boffs[lane] = incl - v;
}

// add block offsets; produce final row_ptr and pos
__global__ void scan3(int* __restrict__ row_ptr, const int* __restrict__ boffs,
                      int* __restrict__ pos) {
    int i = blockIdx.x * SCAN_B + threadIdx.x;
    if (i < N_NODES) {
        int r = row_ptr[i] + boffs[blockIdx.x];
        row_ptr[i] = r;
        pos[i] = r;
    }
    if (i == 0) row_ptr[N_NODES] = N_EDGES;
}

__global__ void scatter_edges(const int* __restrict__ dst, const int* __restrict__ src,
                              int* __restrict__ pos, int* __restrict__ srcs) {
    int i = blockIdx.x * blockDim.x + threadIdx.x;
    if (i < N_EDGES) {
        int p = atomicAdd(&pos[dst[i]], 1);
        srcs[p] = src[i];
    }
}

// ---------------- dense [n,64] @ [64,64] + b (input projection) ----------------
__global__ void mm64_kernel(const float* __restrict__ X, const float* __restrict__ W,
                            const float* __restrict__ b, float* __restrict__ Y, int n) {
    __shared__ float Ws[64][64];
    __shared__ float bs[64];
    int t = threadIdx.x;
    for (int i = t; i < 64 * 64; i += 256) Ws[i >> 6][i & 63] = W[i];
    if (t < 64) bs[t] = b[t];
    __syncthreads();
    int lane = t & 63;
    int rg = t >> 6;
    int base = blockIdx.x * MM_ROWS;
    for (int r = rg; r < MM_ROWS; r += 4) {
        int row = base + r;
        if (row >= n) break;
        const float* x = X + (size_t)row * 64;
        float acc = bs[lane];
#pragma unroll
        for (int k = 0; k < 64; ++k) acc = fmaf(x[k], Ws[k][lane], acc);
        Y[(size_t)row * 64 + lane] = acc;
    }
}

// ---------------- dual dense: fs = h@Ws+bs, fd = h@Wd+bd, register-blocked ----------------
#define DROWS 32
__global__ void mm64_dual(const float* __restrict__ X, const float* __restrict__ Wsg,
                          const float* __restrict__ bsg, const float* __restrict__ Wdg,
                          const float* __restrict__ bdg, float* __restrict__ FS,
                          float* __restrict__ FD, int n) {
    __shared__ float Ws[64][64];
    __shared__ float Wd[64][64];
    __shared__ float xs[4][8][64];
    __shared__ float bsh[64], bdh[64];
    int t = threadIdx.x;
    for (int i = t; i < 4096; i += 256) {
        Ws[i >> 6][i & 63] = Wsg[i];
        Wd[i >> 6][i & 63] = Wdg[i];
    }
    if (t < 64) {
        bsh[t] = bsg[t];
        bdh[t] = bdg[t];
    }
    int lane = t & 63, wv = t >> 6;
    int r0 = blockIdx.x * DROWS + wv * 8;
#pragma unroll
    for (int r = 0; r < 8; ++r) {
        int row = r0 + r;
        xs[wv][r][lane] = (row < n) ? X[(size_t)row * 64 + lane] : 0.f;
    }
    __syncthreads();
    float as[8], ad[8];
    float bsv = bsh[lane], bdv = bdh[lane];
#pragma unroll
    for (int r = 0; r < 8; ++r) {
        as[r] = bsv;
        ad[r] = bdv;
    }
    for (int k4 = 0; k4 < 16; ++k4) {
        int k = k4 * 4;
        float ws0 = Ws[k + 0][lane], ws1 = Ws[k + 1][lane];
        float ws2 = Ws[k + 2][lane], ws3 = Ws[k + 3][lane];
        float wd0 = Wd[k + 0][lane], wd1 = Wd[k + 1][lane];
        float wd2 = Wd[k + 2][lane], wd3 = Wd[k + 3][lane];
#pragma unroll
        for (int r = 0; r < 8; ++r) {
            float4 xv = *(const float4*)&xs[wv][r][k];
            as[r] = fmaf(xv.x, ws0, as[r]);
            as[r] = fmaf(xv.y, ws1, as[r]);
            as[r] = fmaf(xv.z, ws2, as[r]);
            as[r] = fmaf(xv.w, ws3, as[r]);
            ad[r] = fmaf(xv.x, wd0, ad[r]);
            ad[r] = fmaf(xv.y, wd1, ad[r]);
            ad[r] = fmaf(xv.z, wd2, ad[r]);
            ad[r] = fmaf(xv.w, wd3, ad[r]);
        }
    }
#pragma unroll
    for (int r = 0; r < 8; ++r) {
        int row = r0 + r;
        if (row < n) {
            FS[(size_t)row * 64 + lane] = as[r];
            FD[(size_t)row * 64 + lane] = ad[r];
        }
    }
}

// ---------------- fused per-node: scores + online softmax + aggregate + LN + GELU + residual
// 2-way node interleave per wave for ILP/MLP on the latency chain.
#define WPB 4  // waves per block
#define NPW 4  // nodes per wave (2 pairs)
__global__ void node_fused_kernel(const float* __restrict__ fs, const float* __restrict__ fd,
                                  const int* __restrict__ row_ptr, const int* __restrict__ srcs,
                                  const float* __restrict__ attn, const float* __restrict__ gamma,
                                  const float* __restrict__ beta, float* __restrict__ h) {
    int lane = threadIdx.x & 63;
    int wv = threadIdx.x >> 6;
    float aL = attn[lane], gL = gamma[lane], bL = beta[lane];
    int base = blockIdx.x * (WPB * NPW) + wv * NPW;
    for (int p = 0; p < NPW; p += 2) {
        int n0 = base + p, n1 = base + p + 1;
        if (n0 >= N_NODES) break;
        bool has1 = (n1 < N_NODES);
        int beg0 = row_ptr[n0], end0 = row_ptr[n0 + 1];
        int beg1 = has1 ? row_ptr[n1] : 0, end1 = has1 ? row_ptr[n1 + 1] : 0;
        int len0 = end0 - beg0, len1 = end1 - beg1;
        float fdv0 = fd[(size_t)n0 * 64 + lane];
        float fdv1 = has1 ? fd[(size_t)n1 * 64 + lane] : 0.f;
        float m0 = -INFINITY, d0 = 0.f, acc0 = 0.f;
        float m1 = -INFINITY, d1 = 0.f, acc1 = 0.f;
        float row0 = 0.f, row1 = 0.f;
        if (len0 > 0) row0 = fs[(size_t)srcs[beg0] * 64 + lane];
        if (len1 > 0) row1 = fs[(size_t)srcs[beg1] * 64 + lane];
        int L = max(len0, len1);
        for (int j = 0; j < L; ++j) {
            float cur0 = row0, cur1 = row1;
            if (j + 1 < len0) row0 = fs[(size_t)srcs[beg0 + j + 1] * 64 + lane];
            if (j + 1 < len1) row1 = fs[(size_t)srcs[beg1 + j + 1] * 64 + lane];
            // two independent reduce chains, interleaved
            float v0 = cur0 + fdv0;
            v0 = (v0 > 0.f) ? v0 : NEG_SLOPE * v0;
            float v1 = cur1 + fdv1;
            v1 = (v1 > 0.f) ? v1 : NEG_SLOPE * v1;
            float s0 = aL * v0, s1 = aL * v1;
#pragma unroll
            for (int msk = 32; msk >= 1; msk >>= 1) {
                s0 += __shfl_xor(s0, msk, 64);
                s1 += __shfl_xor(s1, msk, 64);
            }
            if (j < len0) {
                if (s0 > m0) {
                    float sca = __expf(m0 - s0);
                    d0 *= sca;
                    acc0 *= sca;
                    m0 = s0;
                }
                float w = __expf(s0 - m0);
                d0 += w;
                acc0 = fmaf(w, cur0, acc0);
            }
            if (j < len1) {
                if (s1 > m1) {
                    float sca = __expf(m1 - s1);
                    d1 *= sca;
                    acc1 *= sca;
                    m1 = s1;
                }
                float w = __expf(s1 - m1);
                d1 += w;
                acc1 = fmaf(w, cur1, acc1);
            }
        }
        acc0 *= (d0 > 0.f) ? 1.f / d0 : 0.f;
        acc1 *= (d1 > 0.f) ? 1.f / d1 : 0.f;
        // layernorm + gelu + residual, both nodes (interleaved reductions)
        float mean0 = acc0, mean1 = acc1;
#pragma unroll
        for (int msk = 32; msk >= 1; msk >>= 1) {
            mean0 += __shfl_xor(mean0, msk, 64);
            mean1 += __shfl_xor(mean1, msk, 64);
        }
        mean0 *= 0.015625f;
        mean1 *= 0.015625f;
        float dev0 = acc0 - mean0, dev1 = acc1 - mean1;
        float var0 = dev0 * dev0, var1 = dev1 * dev1;
#pragma unroll
        for (int msk = 32; msk >= 1; msk >>= 1) {
            var0 += __shfl_xor(var0, msk, 64);
            var1 += __shfl_xor(var1, msk, 64);
        }
        var0 *= 0.015625f;
        var1 *= 0.015625f;
        float t0 = dev0 * rsqrtf(var0 + LN_EPS) * gL + bL;
        float t1 = dev1 * rsqrtf(var1 + LN_EPS) * gL + bL;
        float g0 = 0.5f * t0 * (1.f + erff(t0 * 0.70710678118654752f));
        float g1 = 0.5f * t1 * (1.f + erff(t1 * 0.70710678118654752f));
        h[(size_t)n0 * 64 + lane] += g0;
        if (has1) h[(size_t)n1 * 64 + lane] += g1;
    }
}

// ---------------- output projection [n,64] @ [64,8] + b ----------------
__global__ void out_proj_kernel(const float* __restrict__ h, const float* __restrict__ W,
                                const float* __restrict__ b, float* __restrict__ out) {
    __shared__ float Ws[64 * 8];
    __shared__ float bs[8];
    __shared__ float Hs[32][65];
    int t = threadIdx.x;
    for (int i = t; i < 512; i += 256) Ws[i] = W[i];
    if (t < 8) bs[t] = b[t];
    int n0 = blockIdx.x * 32;
    for (int i = t; i < 32 * 64; i += 256) {
        int r = i >> 6, c = i & 63;
        int n = n0 + r;
        Hs[r][c] = (n < N_NODES) ? h[(size_t)n * 64 + c] : 0.f;
    }
    __syncthreads();
    int nl = t >> 3, o = t & 7;
    int n = n0 + nl;
    if (n >= N_NODES) return;
    float acc = bs[o];
#pragma unroll
    for (int k = 0; k < 64; ++k) acc = fmaf(Hs[nl][k], Ws[k * 8 + o], acc);
    out[(size_t)n * 8 + o] = acc;
}

extern "C" void kernel_launch(void* const* d_in, const int* in_sizes, int n_in,
                              void* d_out, int out_size, void* d_ws, size_t ws_size,
                              hipStream_t stream) {
    const float* nodes = (const float*)d_in[0];
    const int* src = (const int*)d_in[1];
    const int* dst = (const int*)d_in[2];
    const float* w_in = (const float*)d_in[3];
    const float* b_in = (const float*)d_in[4];
    const float* w_src = (const float*)d_in[5];
    const float* b_src = (const float*)d_in[6];
    const float* w_dst = (const float*)d_in[7];
    const float* b_dst = (const float*)d_in[8];
    const float* attn = (const float*)d_in[9];
    const float* gamma = (const float*)d_in[10];
    const float* beta = (const float*)d_in[11];
    const float* w_out = (const float*)d_in[12];
    const float* b_out = (const float*)d_in[13];
    float* out = (float*)d_out;

    char* ws = (char*)d_ws;
    size_t off = 0;
    auto alloc = [&](size_t bytes) {
        void* p = ws + off;
        off += (bytes + 255) & ~(size_t)255;
        return p;
    };
    float* h = (float*)alloc((size_t)N_NODES * 64 * 4);
    float* fs = (float*)alloc((size_t)N_NODES * 64 * 4);
    float* fd = (float*)alloc((size_t)N_NODES * 64 * 4);
    int* deg = (int*)alloc((size_t)N_NODES * 4);
    int* row_ptr = (int*)alloc((size_t)(N_NODES + 1) * 4);
    int* pos = (int*)alloc((size_t)N_NODES * 4);
    int* srcs = (int*)alloc((size_t)N_EDGES * 4);
    int* bsum = (int*)alloc((size_t)NSCAN_BLOCKS * 4);
    int* boffs = (int*)alloc((size_t)NSCAN_BLOCKS * 4);

    // CSR by dst (graph is static across layers); srcs[] = src id in CSR slot order
    hipMemsetAsync(deg, 0, (size_t)N_NODES * 4, stream);
    count_deg<<<(N_EDGES + 255) / 256, 256, 0, stream>>>(dst, deg);
    scan1<<<NSCAN_BLOCKS, SCAN_B, 0, stream>>>(deg, row_ptr, bsum);
    scan2<<<1, 64, 0, stream>>>(bsum, boffs);
    scan3<<<NSCAN_BLOCKS, SCAN_B, 0, stream>>>(row_ptr, boffs, pos);
    scatter_edges<<<(N_EDGES + 255) / 256, 256, 0, stream>>>(dst, src, pos, srcs);

    // input projection
    mm64_kernel<<<(N_NODES + MM_ROWS - 1) / MM_ROWS, 256, 0, stream>>>(nodes, w_in, b_in, h,
                                                                       N_NODES);

    for (int l = 0; l < NLAYERS; ++l) {
        mm64_dual<<<(N_NODES + DROWS - 1) / DROWS, 256, 0, stream>>>(
            h, w_src + (size_t)l * 4096, b_src + (size_t)l * 64, w_dst + (size_t)l * 4096,
            b_dst + (size_t)l * 64, fs, fd, N_NODES);
        node_fused_kernel<<<(N_NODES + WPB * NPW - 1) / (WPB * NPW), 256, 0, stream>>>(
            fs, fd, row_ptr, srcs, attn + (size_t)l * 64, gamma + (size_t)l * 64,
            beta + (size_t)l * 64, h);
    }

    out_proj_kernel<<<(N_NODES + 31) / 32, 256, 0, stream>>>(h, w_out, b_out, out);
}